// Round 2
// baseline (309.232 us; speedup 1.0000x reference)
//
#include <hip/hip_runtime.h>

typedef __attribute__((ext_vector_type(8))) short bf16x8;
typedef __attribute__((ext_vector_type(4))) float floatx4;

static constexpr int SEQ    = 2048;
static constexpr int CDIM   = 1024;
static constexpr int NH     = 16;
static constexpr int HD     = 64;
static constexpr int NBATCH = 2;
static constexpr int MROWS  = NBATCH * SEQ;   // 4096

static __device__ __forceinline__ short f2bf(float f) {
    union { float f; unsigned u; } x; x.f = f;
    unsigned r = x.u + 0x7fffu + ((x.u >> 16) & 1u);   // RNE
    return (short)(r >> 16);
}

static __device__ __forceinline__ floatx4 mfma16(bf16x8 a, bf16x8 b, floatx4 c) {
    return __builtin_amdgcn_mfma_f32_16x16x32_bf16(a, b, c, 0, 0, 0);
}

// ---------------------------------------------------------------------------
// dtype detection: even-index shorts of an f32 stream are mantissa halves
// (uniform random bits -> ~14% plausible bf16 exponents); real bf16 data is
// ~100% plausible. flag = 1 means inputs are float32.
__global__ void detect_dtype(const unsigned short* __restrict__ x, int* __restrict__ flag) {
    const int tid = threadIdx.x;
    int plausible = 0;
    for (int i = tid; i < 8192; i += 256) {
        const unsigned short s = x[2 * i];
        const int e = (s >> 7) & 0xFF;
        if (e >= 110 && e <= 144) plausible++;
    }
    __shared__ int cnt;
    if (tid == 0) cnt = 0;
    __syncthreads();
    atomicAdd(&cnt, plausible);
    __syncthreads();
    if (tid == 0) *flag = (cnt < 4096) ? 1 : 0;
}

// canonicalize an input buffer to bf16 (copy if already bf16, convert if f32)
__global__ void convert_in(const void* __restrict__ src, short* __restrict__ dst,
                           int n, const int* __restrict__ flag) {
    const int f = *flag;
    const int stride = gridDim.x * blockDim.x;
    int i = blockIdx.x * blockDim.x + threadIdx.x;
    if (f) {
        const float* s = (const float*)src;
        for (; i < n; i += stride) dst[i] = f2bf(s[i]);
    } else {
        const short* s = (const short*)src;
        for (; i < n; i += stride) dst[i] = s[i];
    }
}

// ---------------------------------------------------------------------------
// C[m][n] = sum_k A[m][k] * W[n][k]   (torch Linear NT-GEMM), K = CDIM = 1024
// 128x128 tile, BK=32, 4 waves (2x2), each wave 64x64 = 4x4 mfma_16x16x32_bf16
// If flag != nullptr and *flag: C is float*, else C is bf16 (short*).
__global__ __launch_bounds__(256) void gemm_bt128(
    const short* __restrict__ A,
    const short* __restrict__ W0, const short* __restrict__ W1, const short* __restrict__ W2,
    void* __restrict__ C0, void* __restrict__ C1, void* __restrict__ C2,
    const int* __restrict__ flag)
{
    const int m0  = blockIdx.x * 128;
    const int sel = blockIdx.y >> 3;          // which weight matrix (1024/128 = 8 n-tiles each)
    const int n0  = (blockIdx.y & 7) * 128;
    const short* W = (sel == 0) ? W0 : ((sel == 1) ? W1 : W2);
    void*        C = (sel == 0) ? C0 : ((sel == 1) ? C1 : C2);
    const bool f32out = (flag != nullptr) && (*flag != 0);

    __shared__ __align__(16) short ta[128 * 32];
    __shared__ __align__(16) short tb[128 * 32];

    const int tid  = threadIdx.x;
    const int lane = tid & 63;
    const int wave = tid >> 6;
    const int quad = lane >> 4;
    const int l16  = lane & 15;
    const int wm   = (wave >> 1) * 64;
    const int wn   = (wave & 1) * 64;

    floatx4 acc[4][4];
    #pragma unroll
    for (int i = 0; i < 4; i++)
        #pragma unroll
        for (int j = 0; j < 4; j++)
            acc[i][j] = 0.0f;

    // staging: thread t loads 16 bf16 (32 B): row t/2, col chunk (t&1)*16
    const int tr = tid >> 1;
    const int tc = (tid & 1) * 16;
    const short* Ag = A + (m0 + tr) * CDIM + tc;
    const short* Wg = W + (n0 + tr) * CDIM + tc;
    uint4* tap = (uint4*)(ta + tr * 32 + tc);
    uint4* tbp = (uint4*)(tb + tr * 32 + tc);

    for (int k0 = 0; k0 < CDIM; k0 += 32) {
        const uint4* ag = (const uint4*)(Ag + k0);
        const uint4* wg = (const uint4*)(Wg + k0);
        uint4 a0 = ag[0], a1 = ag[1];
        uint4 b0 = wg[0], b1 = wg[1];
        __syncthreads();                       // prev iter's frag reads done
        tap[0] = a0; tap[1] = a1;
        tbp[0] = b0; tbp[1] = b1;
        __syncthreads();

        bf16x8 af[4], bw[4];
        #pragma unroll
        for (int i = 0; i < 4; i++)
            af[i] = *(const bf16x8*)(ta + (wm + i * 16 + l16) * 32 + quad * 8);
        #pragma unroll
        for (int j = 0; j < 4; j++)
            bw[j] = *(const bf16x8*)(tb + (wn + j * 16 + l16) * 32 + quad * 8);
        #pragma unroll
        for (int i = 0; i < 4; i++)
            #pragma unroll
            for (int j = 0; j < 4; j++)
                acc[i][j] = mfma16(af[i], bw[j], acc[i][j]);
    }

    // epilogue: C/D layout row = quad*4+reg, col = l16
    #pragma unroll
    for (int i = 0; i < 4; i++) {
        #pragma unroll
        for (int j = 0; j < 4; j++) {
            const int row = m0 + wm + i * 16 + quad * 4;
            const int col = n0 + wn + j * 16 + l16;
            if (f32out) {
                float* cp = (float*)C + (size_t)row * CDIM + col;
                #pragma unroll
                for (int r = 0; r < 4; r++)
                    cp[(size_t)r * CDIM] = acc[i][j][r];
            } else {
                short* cp = (short*)C + (size_t)row * CDIM + col;
                #pragma unroll
                for (int r = 0; r < 4; r++)
                    cp[(size_t)r * CDIM] = f2bf(acc[i][j][r]);
            }
        }
    }
}

// ---------------------------------------------------------------------------
// Flash-style causal attention. One block = (b, h, 64 q-rows); 4 waves, each owns
// a 16-row q-strip. K-tiles of 64 keys; only kt <= qt visited (uniform per block).
__global__ __launch_bounds__(256) void attn64(
    const short* __restrict__ Q, const short* __restrict__ K,
    const short* __restrict__ V, short* __restrict__ O)
{
    const int qt = blockIdx.x;      // q-tile (64 rows)
    const int h  = blockIdx.y;
    const int b  = blockIdx.z;

    const int tid  = threadIdx.x;
    const int lane = tid & 63;
    const int wave = tid >> 6;
    const int quad = lane >> 4;
    const int l16  = lane & 15;

    __shared__ __align__(16) short Vt[64][80];     // V^T: [d][key], stride 80 (16B-aligned rows)
    __shared__ __align__(16) short Pl[4][16][64];  // per-wave P in [q][key] for A-operand reads

    const int rowBase = b * SEQ;
    const int colH    = h * HD;

    // Q A-operand fragments: Q[q = l16 of strip][d = quad*8 + j], two 32-wide k-chunks
    bf16x8 qfrag0, qfrag1;
    {
        const short* qp = Q + (rowBase + qt * 64 + wave * 16 + l16) * CDIM + colH + quad * 8;
        qfrag0 = *(const bf16x8*)qp;
        qfrag1 = *(const bf16x8*)(qp + 32);
    }

    floatx4 o[4];                   // O accumulator, C-layout: o[nd][r] = (row quad*4+r, col nd*16+l16)
    #pragma unroll
    for (int nd = 0; nd < 4; nd++) o[nd] = 0.0f;
    float m_i[4], l_i[4];
    #pragma unroll
    for (int r = 0; r < 4; r++) { m_i[r] = -1e30f; l_i[r] = 0.0f; }

    const int qg_base = qt * 64 + wave * 16 + quad * 4;   // + r = global q row (within b,h)

    // V staging: thread t -> key = t/4, d-chunk = (t&3)*16 (32 B contiguous global read)
    const int vk = tid >> 2;
    const int vd = (tid & 3) * 16;

    for (int kt = 0; kt <= qt; kt++) {
        // prefetch V rows into regs, then transpose-scatter into LDS
        const short* vp = V + (rowBase + kt * 64 + vk) * CDIM + colH + vd;
        bf16x8 v0 = *(const bf16x8*)vp;
        bf16x8 v1 = *(const bf16x8*)(vp + 8);
        __syncthreads();            // prev iter's PV reads of Vt/Pl complete
        #pragma unroll
        for (int e = 0; e < 8; e++) Vt[vd + e][vk]     = v0[e];
        #pragma unroll
        for (int e = 0; e < 8; e++) Vt[vd + 8 + e][vk] = v1[e];

        // QK^T: scores 16x64 per wave (4 key-subtiles x 2 k-chunks of D)
        floatx4 s[4];
        #pragma unroll
        for (int n = 0; n < 4; n++) {
            const short* kp = K + (rowBase + kt * 64 + n * 16 + l16) * CDIM + colH + quad * 8;
            floatx4 accs = 0.0f;
            accs = mfma16(qfrag0, *(const bf16x8*)kp, accs);
            accs = mfma16(qfrag1, *(const bf16x8*)(kp + 32), accs);
            s[n] = accs;
        }

        // scale + causal mask (exact -10000 like reference) + online softmax per row r
        float p[4][4];
        #pragma unroll
        for (int r = 0; r < 4; r++) {
            const int qg = qg_base + r;
            float mt = -1e30f;
            #pragma unroll
            for (int n = 0; n < 4; n++) {
                float v = s[n][r] * 0.125f;
                const int kg = kt * 64 + n * 16 + l16;
                if (kg > qg) v = -10000.0f;
                p[n][r] = v;
                mt = fmaxf(mt, v);
            }
            #pragma unroll
            for (int off = 1; off < 16; off <<= 1)
                mt = fmaxf(mt, __shfl_xor(mt, off, 64));     // row-max across quad-group
            const float mnew  = fmaxf(m_i[r], mt);
            const float alpha = __expf(m_i[r] - mnew);
            float lsum = 0.0f;
            #pragma unroll
            for (int n = 0; n < 4; n++) {
                const float e = __expf(p[n][r] - mnew);
                p[n][r] = e;
                lsum += e;
            }
            #pragma unroll
            for (int off = 1; off < 16; off <<= 1)
                lsum += __shfl_xor(lsum, off, 64);
            l_i[r] = l_i[r] * alpha + lsum;
            m_i[r] = mnew;
            #pragma unroll
            for (int nd = 0; nd < 4; nd++) o[nd][r] *= alpha;
        }

        // P: C-layout -> LDS [q][key] so it can be re-read in A-operand layout
        #pragma unroll
        for (int n = 0; n < 4; n++)
            #pragma unroll
            for (int r = 0; r < 4; r++)
                Pl[wave][quad * 4 + r][n * 16 + l16] = f2bf(p[n][r]);

        __syncthreads();            // Vt staged + Pl visible

        // PV: O += P(16x64) * V(64x64)
        const bf16x8 pa0 = *(const bf16x8*)&Pl[wave][l16][quad * 8];
        const bf16x8 pa1 = *(const bf16x8*)&Pl[wave][l16][32 + quad * 8];
        #pragma unroll
        for (int nd = 0; nd < 4; nd++) {
            const bf16x8 vb0 = *(const bf16x8*)&Vt[nd * 16 + l16][quad * 8];
            const bf16x8 vb1 = *(const bf16x8*)&Vt[nd * 16 + l16][32 + quad * 8];
            o[nd] = mfma16(pa0, vb0, o[nd]);
            o[nd] = mfma16(pa1, vb1, o[nd]);
        }
    }

    // epilogue: normalize and store O tile (bf16)
    #pragma unroll
    for (int r = 0; r < 4; r++) {
        const float inv = 1.0f / l_i[r];
        short* op = O + (rowBase + qg_base + r) * CDIM + colH + l16;
        #pragma unroll
        for (int nd = 0; nd < 4; nd++)
            op[nd * 16] = f2bf(o[nd][r] * inv);
    }
}

extern "C" void kernel_launch(void* const* d_in, const int* in_sizes, int n_in,
                              void* d_out, int out_size, void* d_ws, size_t ws_size,
                              hipStream_t stream)
{
    const void* x  = d_in[0];
    const void* wq = d_in[1];
    const void* wk = d_in[2];
    const void* wv = d_in[3];
    const void* wo = d_in[4];

    // ws layout (bytes): [0..256) flag, then bf16 buffers
    int* flag = (int*)d_ws;
    short* w = (short*)((char*)d_ws + 256);
    const int ME  = 1024 * 1024;               // 1 Mi elements
    short* Wqc = w;                            // 1M elems (2MB)
    short* Wkc = w + 1 * ME;
    short* Wvc = w + 2 * ME;
    short* Woc = w + 3 * ME;
    short* Xc  = w + 4 * ME;                   // 4M elems (8MB)
    short* Qb  = w + 8 * ME;                   // 4M each
    short* Kb  = w + 12 * ME;
    short* Vb  = w + 16 * ME;
    short* Ob  = Xc;                           // alias: Xc dead after QKV GEMM
    // total: 40MB + 256B of d_ws

    dim3 blk(256);
    detect_dtype<<<1, blk, 0, stream>>>((const unsigned short*)x, flag);

    convert_in<<<2048, blk, 0, stream>>>(x,  Xc,  MROWS * CDIM, flag);
    convert_in<<<1024, blk, 0, stream>>>(wq, Wqc, CDIM * CDIM, flag);
    convert_in<<<1024, blk, 0, stream>>>(wk, Wkc, CDIM * CDIM, flag);
    convert_in<<<1024, blk, 0, stream>>>(wv, Wvc, CDIM * CDIM, flag);
    convert_in<<<1024, blk, 0, stream>>>(wo, Woc, CDIM * CDIM, flag);

    // fused QKV projection: grid.y = 3 mats x 8 n-tiles (bf16 outputs)
    gemm_bt128<<<dim3(MROWS / 128, 24), blk, 0, stream>>>(
        Xc, Wqc, Wkc, Wvc, Qb, Kb, Vb, nullptr);
    // causal flash attention
    attn64<<<dim3(SEQ / 64, NH, NBATCH), blk, 0, stream>>>(Qb, Kb, Vb, Ob);
    // output projection (dtype of d_out per detected input dtype)
    gemm_bt128<<<dim3(MROWS / 128, 8), blk, 0, stream>>>(
        Ob, Woc, Woc, Woc, d_out, d_out, d_out, flag);
}

// Round 3
// 241.147 us; speedup vs baseline: 1.2823x; 1.2823x over previous
//
#include <hip/hip_runtime.h>

typedef __attribute__((ext_vector_type(8))) short bf16x8;
typedef __attribute__((ext_vector_type(4))) float floatx4;

static constexpr int SEQ    = 2048;
static constexpr int CDIM   = 1024;
static constexpr int NH     = 16;
static constexpr int HD     = 64;
static constexpr int NBATCH = 2;
static constexpr int MROWS  = NBATCH * SEQ;   // 4096

static __device__ __forceinline__ short f2bf(float f) {
    union { float f; unsigned u; } x; x.f = f;
    unsigned r = x.u + 0x7fffu + ((x.u >> 16) & 1u);   // RNE
    return (short)(r >> 16);
}

static __device__ __forceinline__ floatx4 mfma16(bf16x8 a, bf16x8 b, floatx4 c) {
    return __builtin_amdgcn_mfma_f32_16x16x32_bf16(a, b, c, 0, 0, 0);
}

// ---------------------------------------------------------------------------
// dtype detection: even-index shorts of an f32 stream are mantissa halves
// (uniform random bits -> ~14% plausible bf16 exponents); real bf16 data is
// ~100% plausible. flag = 1 means inputs are float32.
__global__ void detect_dtype(const unsigned short* __restrict__ x, int* __restrict__ flag) {
    const int tid = threadIdx.x;
    int plausible = 0;
    for (int i = tid; i < 8192; i += 256) {
        const unsigned short s = x[2 * i];
        const int e = (s >> 7) & 0xFF;
        if (e >= 110 && e <= 144) plausible++;
    }
    __shared__ int cnt;
    if (tid == 0) cnt = 0;
    __syncthreads();
    atomicAdd(&cnt, plausible);
    __syncthreads();
    if (tid == 0) *flag = (cnt < 4096) ? 1 : 0;
}

// canonicalize an input buffer to bf16 (copy if already bf16, convert if f32)
__global__ void convert_in(const void* __restrict__ src, short* __restrict__ dst,
                           int n, const int* __restrict__ flag) {
    const int f = *flag;
    const int stride = gridDim.x * blockDim.x;
    int i = blockIdx.x * blockDim.x + threadIdx.x;
    if (f) {
        const float* s = (const float*)src;
        for (; i < n; i += stride) dst[i] = f2bf(s[i]);
    } else {
        const short* s = (const short*)src;
        for (; i < n; i += stride) dst[i] = s[i];
    }
}

// ---------------------------------------------------------------------------
// C[m][n] = sum_k A[m][k] * W[n][k]   (torch Linear NT-GEMM), K = CDIM = 1024
// 128x128 tile, BK=32, 4 waves (2x2), each wave 64x64 = 4x4 mfma_16x16x32_bf16
// If flag != nullptr and *flag: C is float*, else C is bf16 (short*).
__global__ __launch_bounds__(256) void gemm_bt128(
    const short* __restrict__ A,
    const short* __restrict__ W0, const short* __restrict__ W1, const short* __restrict__ W2,
    void* __restrict__ C0, void* __restrict__ C1, void* __restrict__ C2,
    const int* __restrict__ flag)
{
    const int m0  = blockIdx.x * 128;
    const int sel = blockIdx.y >> 3;          // which weight matrix (1024/128 = 8 n-tiles each)
    const int n0  = (blockIdx.y & 7) * 128;
    const short* W = (sel == 0) ? W0 : ((sel == 1) ? W1 : W2);
    void*        C = (sel == 0) ? C0 : ((sel == 1) ? C1 : C2);
    const bool f32out = (flag != nullptr) && (*flag != 0);

    __shared__ __align__(16) short ta[128 * 32];
    __shared__ __align__(16) short tb[128 * 32];

    const int tid  = threadIdx.x;
    const int lane = tid & 63;
    const int wave = tid >> 6;
    const int quad = lane >> 4;
    const int l16  = lane & 15;
    const int wm   = (wave >> 1) * 64;
    const int wn   = (wave & 1) * 64;

    floatx4 acc[4][4];
    #pragma unroll
    for (int i = 0; i < 4; i++)
        #pragma unroll
        for (int j = 0; j < 4; j++)
            acc[i][j] = 0.0f;

    // staging: thread t loads 16 bf16 (32 B): row t/2, col chunk (t&1)*16
    const int tr = tid >> 1;
    const int tc = (tid & 1) * 16;
    const short* Ag = A + (m0 + tr) * CDIM + tc;
    const short* Wg = W + (n0 + tr) * CDIM + tc;
    uint4* tap = (uint4*)(ta + tr * 32 + tc);
    uint4* tbp = (uint4*)(tb + tr * 32 + tc);

    for (int k0 = 0; k0 < CDIM; k0 += 32) {
        const uint4* ag = (const uint4*)(Ag + k0);
        const uint4* wg = (const uint4*)(Wg + k0);
        uint4 a0 = ag[0], a1 = ag[1];
        uint4 b0 = wg[0], b1 = wg[1];
        __syncthreads();                       // prev iter's frag reads done
        tap[0] = a0; tap[1] = a1;
        tbp[0] = b0; tbp[1] = b1;
        __syncthreads();

        bf16x8 af[4], bw[4];
        #pragma unroll
        for (int i = 0; i < 4; i++)
            af[i] = *(const bf16x8*)(ta + (wm + i * 16 + l16) * 32 + quad * 8);
        #pragma unroll
        for (int j = 0; j < 4; j++)
            bw[j] = *(const bf16x8*)(tb + (wn + j * 16 + l16) * 32 + quad * 8);
        #pragma unroll
        for (int i = 0; i < 4; i++)
            #pragma unroll
            for (int j = 0; j < 4; j++)
                acc[i][j] = mfma16(af[i], bw[j], acc[i][j]);
    }

    // epilogue: C/D layout row = quad*4+reg, col = l16
    #pragma unroll
    for (int i = 0; i < 4; i++) {
        #pragma unroll
        for (int j = 0; j < 4; j++) {
            const int row = m0 + wm + i * 16 + quad * 4;
            const int col = n0 + wn + j * 16 + l16;
            if (f32out) {
                float* cp = (float*)C + (size_t)row * CDIM + col;
                #pragma unroll
                for (int r = 0; r < 4; r++)
                    cp[(size_t)r * CDIM] = acc[i][j][r];
            } else {
                short* cp = (short*)C + (size_t)row * CDIM + col;
                #pragma unroll
                for (int r = 0; r < 4; r++)
                    cp[(size_t)r * CDIM] = f2bf(acc[i][j][r]);
            }
        }
    }
}

// ---------------------------------------------------------------------------
// Flash-style causal attention, 128-key k-tiles.
// Grid: (h=16, b=2, z=32). qt = perm[z] so that each CU's 4 resident blocks
// have constant total work (66 64-key tile-equivalents) and heavy blocks are
// dispatched first. One block = 64 q-rows; 4 waves, each owns a 16-row strip.
__global__ __launch_bounds__(256, 4) void attn128(
    const short* __restrict__ Q, const short* __restrict__ K,
    const short* __restrict__ V, short* __restrict__ O)
{
    const int h = blockIdx.x;
    const int b = blockIdx.y;
    // balanced + heavy-first qt permutation over 32 q-tiles
    const int z = blockIdx.z;
    const int u = z & 7, g = z >> 3;
    const int qt = (g == 0) ? (31 - u) : (g == 1) ? u : (g == 2) ? (23 - u) : (8 + u);
    const int nkt = (qt >> 1) + 1;            // number of 128-key tiles

    const int tid  = threadIdx.x;
    const int lane = tid & 63;
    const int wave = tid >> 6;
    const int quad = lane >> 4;
    const int l16  = lane & 15;

    __shared__ __align__(16) short Vt[64][136];     // V^T [d][key(128)], rows padded to 272 B
    __shared__ __align__(16) short Pl[4][16][136];  // per-wave P [q][key(128)], padded

    const int rowBase = b * SEQ;
    const int colH    = h * HD;

    // Q A-operand fragments (16 q-rows per wave, d=64 in two 32-chunks)
    bf16x8 qfrag0, qfrag1;
    {
        const short* qp = Q + (rowBase + qt * 64 + wave * 16 + l16) * CDIM + colH + quad * 8;
        qfrag0 = *(const bf16x8*)qp;
        qfrag1 = *(const bf16x8*)(qp + 32);
    }

    floatx4 o[4];                   // O accumulator, C-layout: o[nd][r] = (q row quad*4+r, d col nd*16+l16)
    #pragma unroll
    for (int nd = 0; nd < 4; nd++) o[nd] = 0.0f;
    float m_i[4], l_i[4];
    #pragma unroll
    for (int r = 0; r < 4; r++) { m_i[r] = -1e30f; l_i[r] = 0.0f; }

    const int qg_base = qt * 64 + wave * 16 + quad * 4;

    // V staging: thread t -> key = t/4 (+64 for 2nd half), d-chunk = (t&3)*16
    const int vk = tid >> 2;
    const int vd = (tid & 3) * 16;

    for (int kt = 0; kt < nkt; kt++) {
        const int key0 = kt * 128;
        // prefetch both 64-key halves of V into regs
        const short* vp  = V + (rowBase + key0 + vk) * CDIM + colH + vd;
        const short* vp2 = vp + 64 * CDIM;
        bf16x8 va0 = *(const bf16x8*)vp;
        bf16x8 va1 = *(const bf16x8*)(vp + 8);
        bf16x8 vb0 = *(const bf16x8*)vp2;
        bf16x8 vb1 = *(const bf16x8*)(vp2 + 8);
        __syncthreads();            // prev iter's PV reads of Vt complete
        #pragma unroll
        for (int e = 0; e < 8; e++) {
            Vt[vd + e][vk]          = va0[e];
            Vt[vd + 8 + e][vk]      = va1[e];
            Vt[vd + e][64 + vk]     = vb0[e];
            Vt[vd + 8 + e][64 + vk] = vb1[e];
        }

        // QK^T: 16x128 scores per wave (8 key-subtiles x 2 d-chunks)
        floatx4 s[8];
        #pragma unroll
        for (int n = 0; n < 8; n++) {
            const short* kp = K + (rowBase + key0 + n * 16 + l16) * CDIM + colH + quad * 8;
            floatx4 a = 0.0f;
            a = mfma16(qfrag0, *(const bf16x8*)kp, a);
            a = mfma16(qfrag1, *(const bf16x8*)(kp + 32), a);
            s[n] = a;
        }

        // scale + causal mask + online softmax (in place on s[])
        #pragma unroll
        for (int r = 0; r < 4; r++) {
            const int qg = qg_base + r;
            float mt = -1e30f;
            #pragma unroll
            for (int n = 0; n < 8; n++) {
                float v = s[n][r] * 0.125f;
                if (key0 + n * 16 + l16 > qg) v = -10000.0f;
                s[n][r] = v;
                mt = fmaxf(mt, v);
            }
            #pragma unroll
            for (int off = 1; off < 16; off <<= 1)
                mt = fmaxf(mt, __shfl_xor(mt, off, 64));
            const float mnew  = fmaxf(m_i[r], mt);
            const float alpha = __expf(m_i[r] - mnew);
            float lsum = 0.0f;
            #pragma unroll
            for (int n = 0; n < 8; n++) {
                const float e = __expf(s[n][r] - mnew);
                s[n][r] = e;
                lsum += e;
            }
            #pragma unroll
            for (int off = 1; off < 16; off <<= 1)
                lsum += __shfl_xor(lsum, off, 64);
            l_i[r] = l_i[r] * alpha + lsum;
            m_i[r] = mnew;
            #pragma unroll
            for (int nd = 0; nd < 4; nd++) o[nd][r] *= alpha;
        }

        // P: C-layout -> LDS [q][key] (A-operand layout for PV)
        #pragma unroll
        for (int n = 0; n < 8; n++)
            #pragma unroll
            for (int r = 0; r < 4; r++)
                Pl[wave][quad * 4 + r][n * 16 + l16] = f2bf(s[n][r]);

        __syncthreads();            // Vt staged (cross-wave) before PV reads

        // PV: O += P(16x128) * V(128x64)
        #pragma unroll
        for (int kc = 0; kc < 4; kc++) {
            const bf16x8 pa = *(const bf16x8*)&Pl[wave][l16][kc * 32 + quad * 8];
            #pragma unroll
            for (int nd = 0; nd < 4; nd++) {
                const bf16x8 vb = *(const bf16x8*)&Vt[nd * 16 + l16][kc * 32 + quad * 8];
                o[nd] = mfma16(pa, vb, o[nd]);
            }
        }
    }

    // epilogue: normalize and store O tile (bf16)
    #pragma unroll
    for (int r = 0; r < 4; r++) {
        const float inv = 1.0f / l_i[r];
        short* op = O + (rowBase + qg_base + r) * CDIM + colH + l16;
        #pragma unroll
        for (int nd = 0; nd < 4; nd++)
            op[nd * 16] = f2bf(o[nd][r] * inv);
    }
}

extern "C" void kernel_launch(void* const* d_in, const int* in_sizes, int n_in,
                              void* d_out, int out_size, void* d_ws, size_t ws_size,
                              hipStream_t stream)
{
    const void* x  = d_in[0];
    const void* wq = d_in[1];
    const void* wk = d_in[2];
    const void* wv = d_in[3];
    const void* wo = d_in[4];

    // ws layout (bytes): [0..256) flag, then bf16 buffers
    int* flag = (int*)d_ws;
    short* w = (short*)((char*)d_ws + 256);
    const int ME  = 1024 * 1024;               // 1 Mi elements
    short* Wqc = w;                            // 1M elems (2MB)
    short* Wkc = w + 1 * ME;
    short* Wvc = w + 2 * ME;
    short* Woc = w + 3 * ME;
    short* Xc  = w + 4 * ME;                   // 4M elems (8MB)
    short* Qb  = w + 8 * ME;                   // 4M each
    short* Kb  = w + 12 * ME;
    short* Vb  = w + 16 * ME;
    short* Ob  = Xc;                           // alias: Xc dead after QKV GEMM
    // total: 40MB + 256B of d_ws

    dim3 blk(256);
    detect_dtype<<<1, blk, 0, stream>>>((const unsigned short*)x, flag);

    convert_in<<<2048, blk, 0, stream>>>(x,  Xc,  MROWS * CDIM, flag);
    convert_in<<<1024, blk, 0, stream>>>(wq, Wqc, CDIM * CDIM, flag);
    convert_in<<<1024, blk, 0, stream>>>(wk, Wkc, CDIM * CDIM, flag);
    convert_in<<<1024, blk, 0, stream>>>(wv, Wvc, CDIM * CDIM, flag);
    convert_in<<<1024, blk, 0, stream>>>(wo, Woc, CDIM * CDIM, flag);

    // fused QKV projection: grid.y = 3 mats x 8 n-tiles (bf16 outputs)
    gemm_bt128<<<dim3(MROWS / 128, 24), blk, 0, stream>>>(
        Xc, Wqc, Wkc, Wvc, Qb, Kb, Vb, nullptr);
    // causal flash attention (balanced qt permutation on grid.z)
    attn128<<<dim3(NH, NBATCH, SEQ / 64), blk, 0, stream>>>(Qb, Kb, Vb, Ob);
    // output projection (dtype of d_out per detected input dtype)
    gemm_bt128<<<dim3(MROWS / 128, 8), blk, 0, stream>>>(
        Ob, Woc, Woc, Woc, d_out, d_out, d_out, flag);
}